// Round 1
// baseline (751.111 us; speedup 1.0000x reference)
//
#include <hip/hip_runtime.h>

// DN4 image-to-class metric, fp32, fully fused.
// C=5 classes, 5 shots, D=64, HW=256, B=75 queries, k=3, k2=64.

#define C_CLS 5
#define SHOTS 5
#define DIM 64
#define HW 256
#define NQ 75
#define K1 3
#define K2 64
#define TILE_M 128          // support descriptors per LDS tile (half a shot)
#define PAD 68              // padded row stride in floats (16B-aligned rows, spreads banks)

__global__ __launch_bounds__(256)
void dn4_kernel(const float* __restrict__ support,
                const float* __restrict__ query,
                float* __restrict__ out) {
    __shared__ float S[TILE_M * PAD];   // support tile, [m][d], padded
    __shared__ float sinv[TILE_M];      // per-descriptor inverse norms

    const int tid = threadIdx.x;
    const int c = blockIdx.x / NQ;
    const int b = blockIdx.x % NQ;

    // ---- load & normalize this thread's query descriptor (q = tid) ----
    const float* qp = query + (size_t)b * DIM * HW + tid;
    float qv[DIM];
    float nq = 0.f;
#pragma unroll
    for (int i = 0; i < DIM; ++i) {
        float v = qp[i * HW];           // coalesced across threads
        qv[i] = v;
        nq += v * v;
    }
    const float invq = rsqrtf(nq);
#pragma unroll
    for (int i = 0; i < DIM; ++i) qv[i] *= invq;

    float t0 = -1e30f, t1 = -1e30f, t2 = -1e30f;   // running top-3 (desc)

    // ---- stream over 10 tiles (5 shots x 2 halves of 128 descriptors) ----
    for (int tile = 0; tile < SHOTS * 2; ++tile) {
        const int shot = tile >> 1;
        const int half = tile & 1;
        const float* sp = support
            + ((size_t)(c * SHOTS + shot)) * DIM * HW + half * TILE_M;

        __syncthreads();                 // previous tile fully consumed
        // stage 128 m x 64 d (8192 floats) with 256 threads x 32 elems
        {
            const int mloc  = tid & (TILE_M - 1);
            const int dbase = tid >> 7;          // 0 or 1
#pragma unroll
            for (int i = 0; i < 32; ++i) {
                int d = 2 * i + dbase;
                S[mloc * PAD + d] = sp[d * HW + mloc];   // coalesced global read
            }
        }
        __syncthreads();
        // per-descriptor inverse norms
        if (tid < TILE_M) {
            const float4* row = (const float4*)&S[tid * PAD];
            float a0 = 0.f, a1 = 0.f, a2 = 0.f, a3 = 0.f;
#pragma unroll
            for (int dd = 0; dd < 16; ++dd) {
                float4 s4 = row[dd];
                a0 = fmaf(s4.x, s4.x, a0);
                a1 = fmaf(s4.y, s4.y, a1);
                a2 = fmaf(s4.z, s4.z, a2);
                a3 = fmaf(s4.w, s4.w, a3);
            }
            sinv[tid] = rsqrtf((a0 + a1) + (a2 + a3));
        }
        __syncthreads();
        // dots: each thread vs all 128 descriptors (LDS reads are broadcasts)
        for (int m = 0; m < TILE_M; ++m) {
            const float4* row = (const float4*)&S[m * PAD];
            float d0 = 0.f, d1 = 0.f, d2 = 0.f, d3 = 0.f;
#pragma unroll
            for (int dd = 0; dd < 16; ++dd) {
                float4 s4 = row[dd];
                d0 = fmaf(s4.x, qv[4 * dd + 0], d0);
                d1 = fmaf(s4.y, qv[4 * dd + 1], d1);
                d2 = fmaf(s4.z, qv[4 * dd + 2], d2);
                d3 = fmaf(s4.w, qv[4 * dd + 3], d3);
            }
            const float sim = ((d0 + d1) + (d2 + d3)) * sinv[m];
            // branchless top-3 insert (order matters: t2 uses old t1, t1 old t0)
            t2 = fmaxf(t2, fminf(sim, t1));
            t1 = fmaxf(t1, fminf(sim, t0));
            t0 = fmaxf(t0, sim);
        }
    }

    // ---- 3 bitonic descending sorts of 256, write top-64 each ----
    float* sbuf = S;   // reuse tile memory
    const size_t obase = ((size_t)(c * NQ + b)) * K1 * K2;
#pragma unroll
    for (int ki = 0; ki < K1; ++ki) {
        const float v = (ki == 0) ? t0 : (ki == 1) ? t1 : t2;
        __syncthreads();                 // prior use of sbuf finished
        sbuf[tid] = v;
        __syncthreads();
        for (int kk = 2; kk <= 256; kk <<= 1) {
            for (int j = kk >> 1; j > 0; j >>= 1) {
                const int ixj = tid ^ j;
                if (ixj > tid) {
                    const float a  = sbuf[tid];
                    const float bb = sbuf[ixj];
                    const bool up = (tid & kk) == 0;
                    const bool sw = up ? (a < bb) : (a > bb);
                    if (sw) { sbuf[tid] = bb; sbuf[ixj] = a; }
                }
                __syncthreads();
            }
        }
        if (tid < K2) out[obase + (size_t)ki * K2 + tid] = sbuf[tid];
    }
}

extern "C" void kernel_launch(void* const* d_in, const int* in_sizes, int n_in,
                              void* d_out, int out_size, void* d_ws, size_t ws_size,
                              hipStream_t stream) {
    const float* support = (const float*)d_in[0];
    const float* query   = (const float*)d_in[1];
    // d_in[2..4] = task_index, k, k2 — fixed by the episode setup (0, 3, 64)
    float* out = (float*)d_out;

    dn4_kernel<<<dim3(C_CLS * NQ), dim3(256), 0, stream>>>(support, query, out);
}

// Round 2
// 377.642 us; speedup vs baseline: 1.9889x; 1.9889x over previous
//
#include <hip/hip_runtime.h>

// DN4 image-to-class, fp32, two-phase for occupancy.
// Phase 1: per (class, query-image, shot) block -> per-query-location top-3 (1875 blocks).
// Phase 2: per (class, query-image, rank) block -> merge 5 shots' top-3, sort top-64 (1125 blocks).

#define C_CLS 5
#define SHOTS 5
#define DIM 64
#define HW 256
#define NQ 75
#define K1 3
#define K2 64
#define TM 64           // support descriptors per LDS tile
#define QSTRIDE 17      // float4 row stride (odd -> conflict-free bank mapping)

__global__ __launch_bounds__(256)
void dn4_phase1(const float* __restrict__ support,
                const float* __restrict__ query,
                float* __restrict__ partial) {
    __shared__ float4 S[TM * QSTRIDE];   // [m][d/4], quad stride 17
    __shared__ float sinv[TM];

    const int tid  = threadIdx.x;
    const int bid  = blockIdx.x;          // ((c*NQ + b)*SHOTS + shot)
    const int shot = bid % SHOTS;
    const int cb   = bid / SHOTS;
    const int b    = cb % NQ;
    const int c    = cb / NQ;

    // ---- this thread's query descriptor (q = tid), normalized, in registers ----
    const float* qp = query + (size_t)b * DIM * HW + tid;
    float qv[DIM];
    float nq = 0.f;
#pragma unroll
    for (int i = 0; i < DIM; ++i) { float v = qp[i * HW]; qv[i] = v; nq = fmaf(v, v, nq); }
    const float invq = rsqrtf(nq);
#pragma unroll
    for (int i = 0; i < DIM; ++i) qv[i] *= invq;

    float t0 = -2.f, t1 = -2.f, t2 = -2.f;   // sims are in [-1,1]

    const float* sp0 = support + (size_t)(c * SHOTS + shot) * DIM * HW;
    const int mloc = tid & (TM - 1);
    const int dg   = tid >> 6;               // 0..3: which 16-d group this thread stages

    for (int tile = 0; tile < HW / TM; ++tile) {
        const float* sp = sp0 + tile * TM + mloc;
        __syncthreads();                     // previous tile fully consumed
        // stage 64 m x 64 d as float4 rows (global reads coalesced along m)
#pragma unroll
        for (int j = 0; j < 4; ++j) {
            float4 v;
            v.x = sp[(dg * 16 + 4 * j + 0) * HW];
            v.y = sp[(dg * 16 + 4 * j + 1) * HW];
            v.z = sp[(dg * 16 + 4 * j + 2) * HW];
            v.w = sp[(dg * 16 + 4 * j + 3) * HW];
            S[mloc * QSTRIDE + dg * 4 + j] = v;   // quad stride 17: conflict-free
        }
        __syncthreads();
        if (tid < TM) {                      // per-descriptor inverse norm
            const float4* row = &S[tid * QSTRIDE];
            float a0 = 0.f, a1 = 0.f, a2 = 0.f, a3 = 0.f;
#pragma unroll
            for (int dd = 0; dd < 16; ++dd) {
                float4 s4 = row[dd];
                a0 = fmaf(s4.x, s4.x, a0); a1 = fmaf(s4.y, s4.y, a1);
                a2 = fmaf(s4.z, s4.z, a2); a3 = fmaf(s4.w, s4.w, a3);
            }
            sinv[tid] = rsqrtf((a0 + a1) + (a2 + a3));
        }
        __syncthreads();
#pragma unroll 4
        for (int m = 0; m < TM; ++m) {
            const float4* row = &S[m * QSTRIDE];   // broadcast reads: conflict-free
            float d0 = 0.f, d1 = 0.f, d2 = 0.f, d3 = 0.f;
#pragma unroll
            for (int dd = 0; dd < 16; ++dd) {
                float4 s4 = row[dd];
                d0 = fmaf(s4.x, qv[4 * dd + 0], d0);
                d1 = fmaf(s4.y, qv[4 * dd + 1], d1);
                d2 = fmaf(s4.z, qv[4 * dd + 2], d2);
                d3 = fmaf(s4.w, qv[4 * dd + 3], d3);
            }
            const float sim = ((d0 + d1) + (d2 + d3)) * sinv[m];
            // branchless top-3 insert (t2 uses old t1, t1 uses old t0)
            t2 = fmaxf(t2, fminf(sim, t1));
            t1 = fmaxf(t1, fminf(sim, t0));
            t0 = fmaxf(t0, sim);
        }
    }

    // partial layout: [c][b][shot][3][HW], coalesced along q=tid
    float* pb = partial + (size_t)bid * K1 * HW + tid;
    pb[0 * HW] = t0;
    pb[1 * HW] = t1;
    pb[2 * HW] = t2;
}

__global__ __launch_bounds__(256)
void dn4_phase2(const float* __restrict__ partial,
                float* __restrict__ out) {
    __shared__ float sbuf[HW];

    const int tid = threadIdx.x;          // query location
    const int bid = blockIdx.x;           // (c*NQ + b)*3 + ki
    const int ki  = bid % K1;
    const int cb  = bid / K1;

    // merge the 5 shots' top-3 (15 values) into a global top-3
    float t0 = -2.f, t1 = -2.f, t2 = -2.f;
    const float* p = partial + (size_t)cb * SHOTS * K1 * HW + tid;
#pragma unroll
    for (int s = 0; s < SHOTS; ++s) {
#pragma unroll
        for (int r = 0; r < K1; ++r) {
            const float v = p[(s * K1 + r) * HW];
            t2 = fmaxf(t2, fminf(v, t1));
            t1 = fmaxf(t1, fminf(v, t0));
            t0 = fmaxf(t0, v);
        }
    }
    const float v = (ki == 0) ? t0 : (ki == 1) ? t1 : t2;

    // bitonic descending sort of 256, write top-64
    sbuf[tid] = v;
    __syncthreads();
    for (int kk = 2; kk <= HW; kk <<= 1) {
        for (int j = kk >> 1; j > 0; j >>= 1) {
            const int ixj = tid ^ j;
            if (ixj > tid) {
                const float a  = sbuf[tid];
                const float bb = sbuf[ixj];
                const bool up = (tid & kk) == 0;
                const bool sw = up ? (a < bb) : (a > bb);
                if (sw) { sbuf[tid] = bb; sbuf[ixj] = a; }
            }
            __syncthreads();
        }
    }
    if (tid < K2) out[(size_t)cb * K1 * K2 + (size_t)ki * K2 + tid] = sbuf[tid];
}

extern "C" void kernel_launch(void* const* d_in, const int* in_sizes, int n_in,
                              void* d_out, int out_size, void* d_ws, size_t ws_size,
                              hipStream_t stream) {
    const float* support = (const float*)d_in[0];
    const float* query   = (const float*)d_in[1];
    float* out     = (float*)d_out;
    float* partial = (float*)d_ws;   // needs C*NQ*SHOTS*3*HW*4 = 5.76 MB

    dn4_phase1<<<dim3(C_CLS * NQ * SHOTS), dim3(256), 0, stream>>>(support, query, partial);
    dn4_phase2<<<dim3(C_CLS * NQ * K1),    dim3(256), 0, stream>>>(partial, out);
}

// Round 3
// 77.090 us; speedup vs baseline: 9.7433x; 4.8987x over previous
//
#include <hip/hip_runtime.h>
#include <stdint.h>

// DN4 image-to-class via bf16 MFMA.
// prep:    normalize support+query descriptors -> bf16 row-major [vec][64]
// dn4_mfma: per (class, 128-col tile, M-half) block; 4 waves x 32 cols;
//           mfma_f32_16x16x32_bf16, per-lane running top-3 (med3 lattice)
// dn4_topq: merge 2x3 partials, bitonic descending sort 256 -> top-64

#define C_CLS 5
#define SHOTS 5
#define DIM 64
#define HW 256
#define NQ 75
#define K1 3
#define K2 64
#define M_TOT (SHOTS * HW)        // 1280 support descriptors per class
#define MSPLIT 2
#define MHALF (M_TOT / MSPLIT)    // 640
#define MSTEPS (MHALF / 16)       // 40

using bf16x8 = __attribute__((ext_vector_type(8))) short;
using f32x4  = __attribute__((ext_vector_type(4))) float;

__device__ inline unsigned short f2bf(float x) {
    uint32_t u = __float_as_uint(x);
    u += 0x7FFF + ((u >> 16) & 1);          // round-to-nearest-even
    return (unsigned short)(u >> 16);
}

// 400 blocks x 64 threads: one descriptor per thread (64 per block).
// blocks [0,300): queries (75 images x 4 chunks); [300,400): support (25 maps x 4 chunks)
__global__ __launch_bounds__(64)
void prep(const float* __restrict__ support, const float* __restrict__ query,
          unsigned short* __restrict__ Sn, unsigned short* __restrict__ Qn) {
    const int bid = blockIdx.x;
    const int t   = threadIdx.x;
    const float* src;
    unsigned short* dst;
    if (bid < NQ * 4) {
        const int b = bid >> 2, q = (bid & 3) * 64 + t;
        src = query + (size_t)b * DIM * HW + q;
        dst = Qn + ((size_t)b * HW + q) * DIM;
    } else {
        const int sb = bid - NQ * 4;
        const int cs = sb >> 2, hw = (sb & 3) * 64 + t;   // cs = c*SHOTS+s
        const int c = cs / SHOTS, s = cs % SHOTS;
        src = support + (size_t)cs * DIM * HW + hw;
        dst = Sn + ((size_t)c * M_TOT + s * HW + hw) * DIM;
    }
    float v[DIM];
    float nrm = 0.f;
#pragma unroll
    for (int d = 0; d < DIM; ++d) { float x = src[d * HW]; v[d] = x; nrm = fmaf(x, x, nrm); }
    const float inv = rsqrtf(nrm);
#pragma unroll
    for (int j = 0; j < 8; ++j) {
        uint4 w;
        w.x = (uint32_t)f2bf(v[8 * j + 0] * inv) | ((uint32_t)f2bf(v[8 * j + 1] * inv) << 16);
        w.y = (uint32_t)f2bf(v[8 * j + 2] * inv) | ((uint32_t)f2bf(v[8 * j + 3] * inv) << 16);
        w.z = (uint32_t)f2bf(v[8 * j + 4] * inv) | ((uint32_t)f2bf(v[8 * j + 5] * inv) << 16);
        w.w = (uint32_t)f2bf(v[8 * j + 6] * inv) | ((uint32_t)f2bf(v[8 * j + 7] * inv) << 16);
        ((uint4*)dst)[j] = w;
    }
}

// grid 1500: bid -> c (5) x ntile (150 of 128 cols) x half (2 of 640 rows)
__global__ __launch_bounds__(256)
void dn4_mfma(const unsigned short* __restrict__ Sn,
              const unsigned short* __restrict__ Qn,
              float* __restrict__ partial) {
    const int tid  = threadIdx.x;
    const int lane = tid & 63;
    const int wv   = tid >> 6;                 // wave 0..3
    const int bid  = blockIdx.x;
    const int c    = bid / 300;
    const int rem  = bid % 300;
    const int half = rem & 1;
    const int nt   = rem >> 1;                 // 0..149
    const int n0   = nt * 128 + wv * 32;       // this wave's first column

    const int lrow = lane & 15;
    const int lk   = lane >> 4;                // k-group 0..3

    // B fragments (query cols), 2 col-groups x 2 k-chunks, loaded once
    bf16x8 bf[2][2];
#pragma unroll
    for (int g = 0; g < 2; ++g) {
        const unsigned short* qp = Qn + ((size_t)(n0 + g * 16 + lrow)) * DIM + lk * 8;
        bf[g][0] = *(const bf16x8*)(qp);
        bf[g][1] = *(const bf16x8*)(qp + 32);
    }

    float t0[2] = {-2.f, -2.f}, t1[2] = {-2.f, -2.f}, t2[2] = {-2.f, -2.f};

    const unsigned short* ap0 =
        Sn + ((size_t)c * M_TOT + half * MHALF + lrow) * DIM + lk * 8;

    for (int ms = 0; ms < MSTEPS; ++ms) {
        const unsigned short* ap = ap0 + (size_t)ms * 16 * DIM;
        const bf16x8 a0 = *(const bf16x8*)(ap);        // k 0..31
        const bf16x8 a1 = *(const bf16x8*)(ap + 32);   // k 32..63
#pragma unroll
        for (int g = 0; g < 2; ++g) {
            f32x4 acc = {0.f, 0.f, 0.f, 0.f};
            acc = __builtin_amdgcn_mfma_f32_16x16x32_bf16(a0, bf[g][0], acc, 0, 0, 0);
            acc = __builtin_amdgcn_mfma_f32_16x16x32_bf16(a1, bf[g][1], acc, 0, 0, 0);
#pragma unroll
            for (int r = 0; r < 4; ++r) {
                const float v = acc[r];
                // running top-3, 3 ops (order matters: t2 uses old t1, t1 old t0)
                t2[g] = __builtin_amdgcn_fmed3f(v, t1[g], t2[g]);
                t1[g] = __builtin_amdgcn_fmed3f(v, t0[g], t1[g]);
                t0[g] = fmaxf(t0[g], v);
            }
        }
    }

    // merge across the 4 lanes sharing each column (lane ^ 16, lane ^ 32)
#pragma unroll
    for (int g = 0; g < 2; ++g) {
#pragma unroll
        for (int off = 16; off < 64; off <<= 1) {
            const float o0 = __shfl_xor(t0[g], off, 64);
            const float o1 = __shfl_xor(t1[g], off, 64);
            const float o2 = __shfl_xor(t2[g], off, 64);
            t2[g] = __builtin_amdgcn_fmed3f(o0, t1[g], t2[g]);
            t1[g] = __builtin_amdgcn_fmed3f(o0, t0[g], t1[g]);
            t0[g] = fmaxf(t0[g], o0);
            t2[g] = __builtin_amdgcn_fmed3f(o1, t1[g], t2[g]);
            t1[g] = __builtin_amdgcn_fmed3f(o1, t0[g], t1[g]);
            t0[g] = fmaxf(t0[g], o1);
            t2[g] = __builtin_amdgcn_fmed3f(o2, t1[g], t2[g]);
            t1[g] = __builtin_amdgcn_fmed3f(o2, t0[g], t1[g]);
            t0[g] = fmaxf(t0[g], o2);
        }
    }

    if (lane < 16) {
#pragma unroll
        for (int g = 0; g < 2; ++g) {
            const int n = n0 + g * 16 + lane;
            const int b = n >> 8, q = n & 255;
            float* pp = partial + (((size_t)(c * NQ + b) * MSPLIT + half) * K1) * HW + q;
            pp[0]      = t0[g];
            pp[HW]     = t1[g];
            pp[2 * HW] = t2[g];
        }
    }
}

// grid 1125: (c*NQ+b)*3 + ki. Merge 2 halves x top-3, bitonic sort 256 desc, write 64.
__global__ __launch_bounds__(256)
void dn4_topq(const float* __restrict__ partial, float* __restrict__ out) {
    __shared__ float sbuf[HW];
    const int tid = threadIdx.x;
    const int bid = blockIdx.x;
    const int ki  = bid % K1;
    const int cb  = bid / K1;

    const float* p = partial + (size_t)cb * MSPLIT * K1 * HW + tid;
    float t0 = -2.f, t1 = -2.f, t2 = -2.f;
#pragma unroll
    for (int h = 0; h < MSPLIT; ++h)
#pragma unroll
        for (int r = 0; r < K1; ++r) {
            const float v = p[(h * K1 + r) * HW];
            t2 = __builtin_amdgcn_fmed3f(v, t1, t2);
            t1 = __builtin_amdgcn_fmed3f(v, t0, t1);
            t0 = fmaxf(t0, v);
        }
    const float v = (ki == 0) ? t0 : (ki == 1) ? t1 : t2;

    sbuf[tid] = v;
    __syncthreads();
    for (int kk = 2; kk <= HW; kk <<= 1) {
        for (int j = kk >> 1; j > 0; j >>= 1) {
            const int ixj = tid ^ j;
            if (ixj > tid) {
                const float a  = sbuf[tid];
                const float bb = sbuf[ixj];
                const bool up = (tid & kk) == 0;
                const bool sw = up ? (a < bb) : (a > bb);
                if (sw) { sbuf[tid] = bb; sbuf[ixj] = a; }
            }
            __syncthreads();
        }
    }
    if (tid < K2) out[(size_t)cb * K1 * K2 + (size_t)ki * K2 + tid] = sbuf[tid];
}

extern "C" void kernel_launch(void* const* d_in, const int* in_sizes, int n_in,
                              void* d_out, int out_size, void* d_ws, size_t ws_size,
                              hipStream_t stream) {
    const float* support = (const float*)d_in[0];
    const float* query   = (const float*)d_in[1];
    float* out = (float*)d_out;

    char* ws = (char*)d_ws;
    unsigned short* Sn = (unsigned short*)ws;                       //   819,200 B
    unsigned short* Qn = (unsigned short*)(ws + 819200);            // 2,457,600 B
    float* partial     = (float*)(ws + 819200 + 2457600);           // 2,304,000 B  (total 5.58 MB)

    prep    <<<dim3(400),  dim3(64),  0, stream>>>(support, query, Sn, Qn);
    dn4_mfma<<<dim3(1500), dim3(256), 0, stream>>>(Sn, Qn, partial);
    dn4_topq<<<dim3(1125), dim3(256), 0, stream>>>(partial, out);
}

// Round 4
// 59.119 us; speedup vs baseline: 12.7050x; 1.3040x over previous
//
#include <hip/hip_runtime.h>
#include <stdint.h>

// DN4 image-to-class via bf16 MFMA, round 4.
// prep:     normalize all descriptors -> bf16 [vec][64]; 4 lanes per descriptor.
// dn4_mfma: per (class, 192-col tile, M-quarter) block; 4 waves x 3 col-groups;
//           prefetched A, dual independent top-3 lattices per group.
// dn4_topq: merge 4x3 bf16 partials, shfl-bitonic descending sort 256 -> top-64.

#define C_CLS 5
#define SHOTS 5
#define DIM 64
#define HW 256
#define NQ 75
#define K1 3
#define K2 64
#define M_TOT (SHOTS * HW)          // 1280
#define MPARTS 4
#define MPART (M_TOT / MPARTS)      // 320
#define MSTEPS (MPART / 16)         // 20
#define NG 3                        // 16-col groups per wave
#define WCOLS (NG * 16)             // 48
#define BCOLS (4 * WCOLS)           // 192
#define NTILES ((NQ * HW) / BCOLS)  // 100

using bf16x8 = __attribute__((ext_vector_type(8))) short;
using f32x4  = __attribute__((ext_vector_type(4))) float;

__device__ inline unsigned short f2bf(float x) {
    uint32_t u = __float_as_uint(x);
    u += 0x7FFF + ((u >> 16) & 1);          // RNE
    return (unsigned short)(u >> 16);
}

// branchless sorted-triple insert; t2 reads old t1, t1 reads old t0
__device__ inline void ins3(float v, float& t0, float& t1, float& t2) {
    t2 = __builtin_amdgcn_fmed3f(v, t1, t2);
    t1 = __builtin_amdgcn_fmed3f(v, t0, t1);
    t0 = fmaxf(t0, v);
}

// 400 blocks x 256 threads; each wave: 16 descriptors x 4 d-groups of 16.
__global__ __launch_bounds__(256)
void prep(const float* __restrict__ support, const float* __restrict__ query,
          unsigned short* __restrict__ Sn, unsigned short* __restrict__ Qn) {
    const int tid  = threadIdx.x;
    const int wv   = tid >> 6, lane = tid & 63;
    const int dg   = lane >> 4, dl = lane & 15;
    const int bid  = blockIdx.x;
    const float* src;
    unsigned short* dst;
    if (bid < NQ * 4) {
        const int b    = bid >> 2;
        const int desc = (bid & 3) * 64 + wv * 16 + dl;
        src = query + (size_t)b * DIM * HW + desc;
        dst = Qn + ((size_t)b * HW + desc) * DIM + dg * 16;
    } else {
        const int sb   = bid - NQ * 4;
        const int cs   = sb >> 2;                      // c*SHOTS + s
        const int desc = (sb & 3) * 64 + wv * 16 + dl;
        const int c = cs / SHOTS, s = cs % SHOTS;
        src = support + (size_t)cs * DIM * HW + desc;
        dst = Sn + ((size_t)c * M_TOT + s * HW + desc) * DIM + dg * 16;
    }
    float v[16];
    float nrm = 0.f;
#pragma unroll
    for (int i = 0; i < 16; ++i) {
        const float x = src[(dg * 16 + i) * HW];
        v[i] = x; nrm = fmaf(x, x, nrm);
    }
    nrm += __shfl_xor(nrm, 16, 64);      // reduce over the 4 d-groups
    nrm += __shfl_xor(nrm, 32, 64);
    const float inv = rsqrtf(nrm);
    uint32_t p[8];
#pragma unroll
    for (int j = 0; j < 8; ++j)
        p[j] = (uint32_t)f2bf(v[2 * j] * inv) | ((uint32_t)f2bf(v[2 * j + 1] * inv) << 16);
    const uint4 w0 = {p[0], p[1], p[2], p[3]}, w1 = {p[4], p[5], p[6], p[7]};
    ((uint4*)dst)[0] = w0;
    ((uint4*)dst)[1] = w1;
}

// grid 2000: c (5) x ntile (100) x part (4)
__global__ __launch_bounds__(256)
void dn4_mfma(const unsigned short* __restrict__ Sn,
              const unsigned short* __restrict__ Qn,
              unsigned short* __restrict__ partial) {
    const int tid  = threadIdx.x;
    const int lane = tid & 63, wv = tid >> 6;
    const int bid  = blockIdx.x;
    const int c    = bid / (NTILES * MPARTS);
    const int rem  = bid % (NTILES * MPARTS);
    const int nt   = rem / MPARTS, part = rem % MPARTS;
    const int n0   = nt * BCOLS + wv * WCOLS;
    const int lrow = lane & 15, lk = lane >> 4;

    bf16x8 bfr[NG][2];                       // B fragments, loaded once
#pragma unroll
    for (int g = 0; g < NG; ++g) {
        const unsigned short* qp = Qn + (size_t)(n0 + g * 16 + lrow) * DIM + lk * 8;
        bfr[g][0] = *(const bf16x8*)qp;
        bfr[g][1] = *(const bf16x8*)(qp + 32);
    }

    float t0[NG][2], t1[NG][2], t2[NG][2];   // 2 independent lattices per group
#pragma unroll
    for (int g = 0; g < NG; ++g)
#pragma unroll
        for (int p = 0; p < 2; ++p) { t0[g][p] = -2.f; t1[g][p] = -2.f; t2[g][p] = -2.f; }

    const unsigned short* ap0 =
        Sn + ((size_t)c * M_TOT + part * MPART + lrow) * DIM + lk * 8;
    bf16x8 a0 = *(const bf16x8*)ap0;         // k 0..31
    bf16x8 a1 = *(const bf16x8*)(ap0 + 32);  // k 32..63

    for (int ms = 0; ms < MSTEPS; ++ms) {
        const int msn = (ms + 1 < MSTEPS) ? ms + 1 : ms;     // clamped prefetch
        const unsigned short* apn = ap0 + (size_t)msn * 16 * DIM;
        const bf16x8 na0 = *(const bf16x8*)apn;
        const bf16x8 na1 = *(const bf16x8*)(apn + 32);
#pragma unroll
        for (int g = 0; g < NG; ++g) {
            f32x4 acc = {0.f, 0.f, 0.f, 0.f};
            acc = __builtin_amdgcn_mfma_f32_16x16x32_bf16(a0, bfr[g][0], acc, 0, 0, 0);
            acc = __builtin_amdgcn_mfma_f32_16x16x32_bf16(a1, bfr[g][1], acc, 0, 0, 0);
#pragma unroll
            for (int p = 0; p < 2; ++p) {
                ins3(acc[2 * p],     t0[g][p], t1[g][p], t2[g][p]);
                ins3(acc[2 * p + 1], t0[g][p], t1[g][p], t2[g][p]);
            }
        }
        a0 = na0; a1 = na1;
    }

#pragma unroll
    for (int g = 0; g < NG; ++g) {
        // merge lattice 1 into lattice 0
        ins3(t0[g][1], t0[g][0], t1[g][0], t2[g][0]);
        ins3(t1[g][1], t0[g][0], t1[g][0], t2[g][0]);
        ins3(t2[g][1], t0[g][0], t1[g][0], t2[g][0]);
        // merge across the 4 k-group lanes of each column
#pragma unroll
        for (int off = 16; off < 64; off <<= 1) {
            const float o0 = __shfl_xor(t0[g][0], off, 64);
            const float o1 = __shfl_xor(t1[g][0], off, 64);
            const float o2 = __shfl_xor(t2[g][0], off, 64);
            ins3(o0, t0[g][0], t1[g][0], t2[g][0]);
            ins3(o1, t0[g][0], t1[g][0], t2[g][0]);
            ins3(o2, t0[g][0], t1[g][0], t2[g][0]);
        }
    }

    if (lane < 16) {
#pragma unroll
        for (int g = 0; g < NG; ++g) {
            const int n = n0 + g * 16 + lane;
            const int b = n >> 8, q = n & 255;
            unsigned short* pp =
                partial + (((size_t)(c * NQ + b) * MPARTS + part) * K1) * HW + q;
            pp[0]      = f2bf(t0[g][0]);
            pp[HW]     = f2bf(t1[g][0]);
            pp[2 * HW] = f2bf(t2[g][0]);
        }
    }
}

// grid 1125: (c*NQ+b)*3 + ki. Merge 4 parts x top-3, shfl-bitonic sort, write 64.
__global__ __launch_bounds__(256)
void dn4_topq(const unsigned short* __restrict__ partial, float* __restrict__ out) {
    __shared__ float sbuf[HW];
    const int tid = threadIdx.x;
    const int bid = blockIdx.x;
    const int ki  = bid % K1;
    const int cb  = bid / K1;

    const unsigned short* p = partial + (size_t)cb * MPARTS * K1 * HW + tid;
    float t0 = -2.f, t1 = -2.f, t2 = -2.f;
#pragma unroll
    for (int h = 0; h < MPARTS; ++h)
#pragma unroll
        for (int r = 0; r < K1; ++r) {
            const float v = __uint_as_float((uint32_t)p[(h * K1 + r) * HW] << 16);
            ins3(v, t0, t1, t2);
        }
    float v = (ki == 0) ? t0 : (ki == 1) ? t1 : t2;

    // bitonic descending sort of 256: registers + shfl for j<64, LDS for j>=64
#pragma unroll
    for (int kk = 2; kk <= HW; kk <<= 1) {
#pragma unroll
        for (int j = kk >> 1; j > 0; j >>= 1) {
            const bool keep_max = (((tid & kk) == 0) == ((tid & j) == 0));
            float w;
            if (j >= 64) {
                sbuf[tid] = v;
                __syncthreads();
                w = sbuf[tid ^ j];
                __syncthreads();
            } else {
                w = __shfl_xor(v, j, 64);
            }
            v = keep_max ? fmaxf(v, w) : fminf(v, w);
        }
    }
    if (tid < K2) out[(size_t)cb * K1 * K2 + (size_t)ki * K2 + tid] = v;
}

extern "C" void kernel_launch(void* const* d_in, const int* in_sizes, int n_in,
                              void* d_out, int out_size, void* d_ws, size_t ws_size,
                              hipStream_t stream) {
    const float* support = (const float*)d_in[0];
    const float* query   = (const float*)d_in[1];
    float* out = (float*)d_out;

    char* ws = (char*)d_ws;
    unsigned short* Sn      = (unsigned short*)ws;                     //   819,200 B
    unsigned short* Qn      = (unsigned short*)(ws + 819200);          // 2,457,600 B
    unsigned short* partial = (unsigned short*)(ws + 819200 + 2457600);// 2,304,000 B (total 5.58 MB)

    prep    <<<dim3(400),                     dim3(256), 0, stream>>>(support, query, Sn, Qn);
    dn4_mfma<<<dim3(C_CLS * NTILES * MPARTS), dim3(256), 0, stream>>>(Sn, Qn, partial);
    dn4_topq<<<dim3(C_CLS * NQ * K1),         dim3(256), 0, stream>>>(partial, out);
}

// Round 5
// 46.403 us; speedup vs baseline: 16.1866x; 1.2740x over previous
//
#include <hip/hip_runtime.h>
#include <stdint.h>

// DN4 image-to-class via bf16 MFMA, round 5.
// prep:     normalize all descriptors -> bf16 [vec][64].
// dn4_mfma: block = (class, M-part, 128-query tile). Support tiles staged to LDS
//           via global_load_lds with pre-swizzled source; transposed MFMA mapping
//           (A = queries, B = support) -> 8 independent top-3 lattices per lane.
// dn4_topq: merge 2x3 bf16 partials, shfl-bitonic descending sort 256 -> top-64.

#define C_CLS 5
#define SHOTS 5
#define DIM 64
#define HW 256
#define NQ 75
#define K1 3
#define K2 64
#define M_TOT 1280
#define MPARTS 2
#define MPART 640
#define NIT 5                 // 128-row support tiles per part
#define QBLK 128              // queries per block
#define NTILES 150            // 19200 / 128

using bf16x8 = __attribute__((ext_vector_type(8))) short;
using f32x4  = __attribute__((ext_vector_type(4))) float;

typedef __attribute__((address_space(1))) const unsigned int GU32;
typedef __attribute__((address_space(3))) unsigned int LU32;

__device__ __forceinline__ void gload16(const void* g, void* l) {
    __builtin_amdgcn_global_load_lds((GU32*)g, (LU32*)l, 16, 0, 0);
}

// XOR swizzle on a byte offset within a [128 rows][128 B] tile (involution)
#define SWZ(o) ((o) ^ ((((o) >> 7) & 7) << 4))

__device__ inline unsigned short f2bf(float x) {
    uint32_t u = __float_as_uint(x);
    u += 0x7FFF + ((u >> 16) & 1);          // RNE
    return (unsigned short)(u >> 16);
}

// branchless sorted-triple insert; t2 reads old t1, t1 reads old t0
__device__ __forceinline__ void ins3(float v, float& t0, float& t1, float& t2) {
    t2 = __builtin_amdgcn_fmed3f(v, t1, t2);
    t1 = __builtin_amdgcn_fmed3f(v, t0, t1);
    t0 = fmaxf(t0, v);
}

// 400 blocks x 256 threads; each wave: 16 descriptors x 4 d-groups of 16.
__global__ __launch_bounds__(256)
void prep(const float* __restrict__ support, const float* __restrict__ query,
          unsigned short* __restrict__ Sn, unsigned short* __restrict__ Qn) {
    const int tid  = threadIdx.x;
    const int wv   = tid >> 6, lane = tid & 63;
    const int dg   = lane >> 4, dl = lane & 15;
    const int bid  = blockIdx.x;
    const float* src;
    unsigned short* dst;
    if (bid < NQ * 4) {
        const int b    = bid >> 2;
        const int desc = (bid & 3) * 64 + wv * 16 + dl;
        src = query + (size_t)b * DIM * HW + desc;
        dst = Qn + ((size_t)b * HW + desc) * DIM + dg * 16;
    } else {
        const int sb   = bid - NQ * 4;
        const int cs   = sb >> 2;                      // c*SHOTS + s
        const int desc = (sb & 3) * 64 + wv * 16 + dl;
        const int c = cs / SHOTS, s = cs % SHOTS;
        src = support + (size_t)cs * DIM * HW + desc;
        dst = Sn + ((size_t)c * M_TOT + s * HW + desc) * DIM + dg * 16;
    }
    float v[16];
    float nrm = 0.f;
#pragma unroll
    for (int i = 0; i < 16; ++i) {
        const float x = src[(dg * 16 + i) * HW];
        v[i] = x; nrm = fmaf(x, x, nrm);
    }
    nrm += __shfl_xor(nrm, 16, 64);
    nrm += __shfl_xor(nrm, 32, 64);
    const float inv = rsqrtf(nrm);
    uint32_t p[8];
#pragma unroll
    for (int j = 0; j < 8; ++j)
        p[j] = (uint32_t)f2bf(v[2 * j] * inv) | ((uint32_t)f2bf(v[2 * j + 1] * inv) << 16);
    const uint4 w0 = {p[0], p[1], p[2], p[3]}, w1 = {p[4], p[5], p[6], p[7]};
    ((uint4*)dst)[0] = w0;
    ((uint4*)dst)[1] = w1;
}

// grid 1500: c(5) x part(2) x nt(150)
__global__ __launch_bounds__(256, 6)
void dn4_mfma(const unsigned short* __restrict__ Sn,
              const unsigned short* __restrict__ Qn,
              unsigned short* __restrict__ partial) {
    __shared__ unsigned short sB[128 * DIM];   // 16 KB support tile, swizzled layout

    const int tid  = threadIdx.x;
    const int lane = tid & 63, w = tid >> 6;
    const int c15  = lane & 15, kg = lane >> 4;
    const int bid  = blockIdx.x;
    const int c    = bid / 300;
    const int rem  = bid % 300;
    const int part = rem / NTILES;
    const int nt   = rem % NTILES;

    // ---- A fragments: this wave's 32 queries (2 groups of 16), gathered once ----
    const int q0 = nt * QBLK + w * 32;
    bf16x8 aq[2][2];
#pragma unroll
    for (int g = 0; g < 2; ++g) {
        const unsigned short* qp = Qn + (size_t)(q0 + g * 16 + c15) * DIM + kg * 8;
        aq[g][0] = *(const bf16x8*)qp;          // k 0..31
        aq[g][1] = *(const bf16x8*)(qp + 32);   // k 32..63
    }

    // 8 independent lattices: [group][acc-reg] -> query kg*4+r (+g*16)
    float t0[2][4], t1[2][4], t2[2][4];
#pragma unroll
    for (int g = 0; g < 2; ++g)
#pragma unroll
        for (int r = 0; r < 4; ++r) { t0[g][r] = -2.f; t1[g][r] = -2.f; t2[g][r] = -2.f; }

    // per-lane swizzled LDS byte offsets for B fragments
    const int sw   = (c15 & 7) << 4;
    const int off0 = (kg * 16) ^ sw;            // k 0..31 chunk
    const int off1 = (kg * 16 + 64) ^ sw;       // k 32..63 chunk
    const int rowb = c15 * 128;

    const unsigned short* tb0 =
        Sn + ((size_t)c * M_TOT + part * MPART) * DIM;   // this part's 640 rows

    for (int it = 0; it < NIT; ++it) {
        __syncthreads();                         // previous tile fully consumed
        // ---- stage 128x64 bf16 tile via global_load_lds, pre-swizzled source ----
        {
            const char* tb = (const char*)(tb0 + (size_t)it * 128 * DIM);
#pragma unroll
            for (int rep = 0; rep < 4; ++rep) {
                const int o = rep * 4096 + w * 1024 + lane * 16;   // LDS byte offset
                gload16(tb + SWZ(o), (char*)sB + rep * 4096 + w * 1024);
            }
        }
        __syncthreads();                         // compiler drains vmcnt before barrier

        // ---- 8 support steps of 16 descriptors ----
#pragma unroll
        for (int ns = 0; ns < 8; ++ns) {
            const char* rp = (const char*)sB + rowb + ns * 2048;
            const bf16x8 b0 = *(const bf16x8*)(rp + off0);
            const bf16x8 b1 = *(const bf16x8*)(rp + off1);
#pragma unroll
            for (int g = 0; g < 2; ++g) {
                f32x4 acc = {0.f, 0.f, 0.f, 0.f};
                acc = __builtin_amdgcn_mfma_f32_16x16x32_bf16(aq[g][0], b0, acc, 0, 0, 0);
                acc = __builtin_amdgcn_mfma_f32_16x16x32_bf16(aq[g][1], b1, acc, 0, 0, 0);
#pragma unroll
                for (int r = 0; r < 4; ++r)
                    ins3(acc[r], t0[g][r], t1[g][r], t2[g][r]);   // 1 insert per lattice
            }
        }
    }

    // ---- merge across the 16 support-columns lanes (same kg group) ----
#pragma unroll
    for (int g = 0; g < 2; ++g)
#pragma unroll
        for (int r = 0; r < 4; ++r)
#pragma unroll
            for (int off = 1; off < 16; off <<= 1) {
                const float o0 = __shfl_xor(t0[g][r], off, 64);
                const float o1 = __shfl_xor(t1[g][r], off, 64);
                const float o2 = __shfl_xor(t2[g][r], off, 64);
                ins3(o0, t0[g][r], t1[g][r], t2[g][r]);
                ins3(o1, t0[g][r], t1[g][r], t2[g][r]);
                ins3(o2, t0[g][r], t1[g][r], t2[g][r]);
            }

    if (c15 == 0) {
        const int b = nt >> 1;
        unsigned short* pbase =
            partial + (((size_t)(c * NQ + b) * MPARTS + part) * K1) * HW;
#pragma unroll
        for (int g = 0; g < 2; ++g)
#pragma unroll
            for (int r = 0; r < 4; ++r) {
                const int qloc = (nt & 1) * QBLK + w * 32 + g * 16 + kg * 4 + r;
                pbase[qloc]          = f2bf(t0[g][r]);
                pbase[HW + qloc]     = f2bf(t1[g][r]);
                pbase[2 * HW + qloc] = f2bf(t2[g][r]);
            }
    }
}

// grid 1125: (c*NQ+b)*3 + ki. Merge 2 parts x top-3, shfl-bitonic sort, write 64.
__global__ __launch_bounds__(256)
void dn4_topq(const unsigned short* __restrict__ partial, float* __restrict__ out) {
    __shared__ float sbuf[HW];
    const int tid = threadIdx.x;
    const int bid = blockIdx.x;
    const int ki  = bid % K1;
    const int cb  = bid / K1;

    const unsigned short* p = partial + (size_t)cb * MPARTS * K1 * HW + tid;
    float t0 = -2.f, t1 = -2.f, t2 = -2.f;
#pragma unroll
    for (int h = 0; h < MPARTS; ++h)
#pragma unroll
        for (int r = 0; r < K1; ++r) {
            const float v = __uint_as_float((uint32_t)p[(h * K1 + r) * HW] << 16);
            ins3(v, t0, t1, t2);
        }
    float v = (ki == 0) ? t0 : (ki == 1) ? t1 : t2;

#pragma unroll
    for (int kk = 2; kk <= HW; kk <<= 1) {
#pragma unroll
        for (int j = kk >> 1; j > 0; j >>= 1) {
            const bool keep_max = (((tid & kk) == 0) == ((tid & j) == 0));
            float wv;
            if (j >= 64) {
                sbuf[tid] = v;
                __syncthreads();
                wv = sbuf[tid ^ j];
                __syncthreads();
            } else {
                wv = __shfl_xor(v, j, 64);
            }
            v = keep_max ? fmaxf(v, wv) : fminf(v, wv);
        }
    }
    if (tid < K2) out[(size_t)cb * K1 * K2 + (size_t)ki * K2 + tid] = v;
}

extern "C" void kernel_launch(void* const* d_in, const int* in_sizes, int n_in,
                              void* d_out, int out_size, void* d_ws, size_t ws_size,
                              hipStream_t stream) {
    const float* support = (const float*)d_in[0];
    const float* query   = (const float*)d_in[1];
    float* out = (float*)d_out;

    char* ws = (char*)d_ws;
    unsigned short* Sn      = (unsigned short*)ws;                      //   819,200 B
    unsigned short* Qn      = (unsigned short*)(ws + 819200);           // 2,457,600 B
    unsigned short* partial = (unsigned short*)(ws + 819200 + 2457600); // 1,152,000 B (4.43 MB total)

    prep    <<<dim3(400),                      dim3(256), 0, stream>>>(support, query, Sn, Qn);
    dn4_mfma<<<dim3(C_CLS * MPARTS * NTILES),  dim3(256), 0, stream>>>(Sn, Qn, partial);
    dn4_topq<<<dim3(C_CLS * NQ * K1),          dim3(256), 0, stream>>>(partial, out);
}